// Round 8
// baseline (688.542 us; speedup 1.0000x reference)
//
#include <hip/hip_runtime.h>
#include <hip/hip_bf16.h>

#define HIDDEN  128
#define NUM_RBF 50
#define CUTOFF  5.0f
#define INV_WIDTH (49.0f / 5.0f)
#define OFF_STEP  (5.0f / 49.0f)
#define PI_F 3.14159265358979f

// LDS row stride (halfs). 136 = 128+8: rows 16B-aligned (272 B) and fragment
// reads land 2-way bank-aliased (free per m136).
#define PK2 136
#define PT  136

typedef __attribute__((ext_vector_type(8))) short short8;   // 8 bf16 (4 VGPR)
typedef __attribute__((ext_vector_type(4))) float floatx4;  // MFMA acc

__device__ __forceinline__ unsigned short f2bf(float x) {
    union { float f; unsigned int u; } v; v.f = x;
    return (unsigned short)((v.u + 0x7fff + ((v.u >> 16) & 1)) >> 16);  // RNE
}

__device__ __forceinline__ float silu(float x) {
    return x / (1.0f + __expf(-x));
}

// ---------------------------------------------------------------------------
// Counting-sort / CSR pipeline (scratch lives in d_out; node kernel overwrites
// d_out only at the very end). rowptr doubles as CSR index for the
// node-centric edge kernel.
// ---------------------------------------------------------------------------
__global__ void hist_kernel(const int* __restrict__ ei, int* __restrict__ cnt,
                            int n_nodes, int n_edges)
{
    for (int e = blockIdx.x * blockDim.x + threadIdx.x; e < n_edges;
         e += gridDim.x * blockDim.x) {
        const int r = min(max(ei[e], 0), n_nodes - 1);
        atomicAdd(&cnt[r], 1);
    }
}

// Local exclusive scan over 256-bin segments; emits per-segment totals.
__global__ __launch_bounds__(256) void scanA_kernel(const int* __restrict__ cnt,
                                                    int* __restrict__ cursor,
                                                    int* __restrict__ btot,
                                                    int nb)
{
    __shared__ int s[256];
    const int t = threadIdx.x;
    const int i = blockIdx.x * 256 + t;
    const int v = (i < nb) ? cnt[i] : 0;
    s[t] = v;
    __syncthreads();
#pragma unroll
    for (int off = 1; off < 256; off <<= 1) {
        const int u = (t >= off) ? s[t - off] : 0;
        __syncthreads();
        s[t] += u;
        __syncthreads();
    }
    if (i < nb) cursor[i] = s[t] - v;           // local exclusive prefix
    if (t == 255) btot[blockIdx.x] = s[255];    // segment total
}

// Single small block: exclusive scan of segment totals.
__global__ __launch_bounds__(256) void scanB_kernel(const int* __restrict__ btot,
                                                    int* __restrict__ boff,
                                                    int nblk)
{
    __shared__ int s[256];
    const int t = threadIdx.x;
    const int v = (t < nblk) ? btot[t] : 0;
    s[t] = v;
    __syncthreads();
#pragma unroll
    for (int off = 1; off < 256; off <<= 1) {
        const int u = (t >= off) ? s[t - off] : 0;
        __syncthreads();
        s[t] += u;
        __syncthreads();
    }
    if (t < nblk) boff[t] = s[t] - v;
}

// rowptr[r] = boff[r>>8] + cursor[r]; working cursor copy for scatter.
__global__ void finalize_kernel(const int* __restrict__ cursor,
                                const int* __restrict__ boff,
                                int* __restrict__ rp, int* __restrict__ wcur,
                                int n_nodes, int n_edges)
{
    const int i = blockIdx.x * blockDim.x + threadIdx.x;
    if (i < n_nodes) {
        const int v = boff[i >> 8] + cursor[i];
        rp[i] = v;
        wcur[i] = v;
    }
    if (i == n_nodes) rp[n_nodes] = n_edges;
}

__global__ void scatter_kernel(const int* __restrict__ ei,
                               const float* __restrict__ pos,
                               int* __restrict__ wcur,
                               int* __restrict__ scol,
                               float* __restrict__ sdist,
                               int n_nodes, int n_edges)
{
    for (int e = blockIdx.x * blockDim.x + threadIdx.x; e < n_edges;
         e += gridDim.x * blockDim.x) {
        const int r = min(max(ei[e], 0), n_nodes - 1);
        const int c = min(max(ei[n_edges + e], 0), n_nodes - 1);
        const float dx = pos[r * 3 + 0] - pos[c * 3 + 0];
        const float dy = pos[r * 3 + 1] - pos[c * 3 + 1];
        const float dz = pos[r * 3 + 2] - pos[c * 3 + 2];
        const float dist = sqrtf(dx * dx + dy * dy + dz * dz + 1e-8f);
        const int p = atomicAdd(&wcur[r], 1);
        scol[p] = c;
        sdist[p] = dist;
    }
}

// ---------------------------------------------------------------------------
// Node-centric edge kernel: one wave per destination node (grid-stride).
// The wave loops over the node's <=16-edge CSR tiles, runs the MFMA filter
// pipeline, multiplies by cut*h[col], and accumulates in registers. One
// shfl_xor reduction + coalesced store per node. ZERO atomics.
// ---------------------------------------------------------------------------
__global__ __launch_bounds__(256) void edge_mfma_csr_kernel(
    const float* __restrict__ h,
    const int* __restrict__ rp,
    const int* __restrict__ scol,
    const float* __restrict__ sdist,
    const float* __restrict__ fw1,
    const float* __restrict__ fb1,
    const float* __restrict__ fw2,
    const float* __restrict__ fb2,
    float* __restrict__ agg,
    int n_nodes)
{
    __shared__ __attribute__((aligned(16))) unsigned short fw2T[128 * PK2];
    __shared__ __attribute__((aligned(16))) unsigned short tbuf[4 * 16 * PT];

    const int tid  = threadIdx.x;
    const int wave = tid >> 6;
    const int lane = tid & 63;
    const int l15  = lane & 15;
    const int quad = lane >> 4;

    // stage fw2 transposed (bf16): fw2T[n][k] = fw2[k][n]
    for (int idx = tid; idx < HIDDEN * HIDDEN; idx += 256) {
        const int k = idx >> 7, n = idx & 127;
        fw2T[n * PK2 + k] = f2bf(fw2[idx]);
    }

    // fw1 B-fragments in registers (zero rows k>=50)
    short8 b1[2][8];
#pragma unroll
    for (int kit = 0; kit < 2; ++kit)
#pragma unroll
        for (int nt = 0; nt < 8; ++nt) {
            short8 f;
#pragma unroll
            for (int j = 0; j < 8; ++j) {
                const int k = kit * 32 + quad * 8 + j;
                const int n = nt * 16 + l15;
                f[j] = (k < NUM_RBF) ? (short)f2bf(fw1[k * HIDDEN + n]) : (short)0;
            }
            b1[kit][nt] = f;
        }

    float fb1v[8], fb2v[8];
#pragma unroll
    for (int nt = 0; nt < 8; ++nt) {
        fb1v[nt] = fb1[nt * 16 + l15];
        fb2v[nt] = fb2[nt * 16 + l15];
    }

    __syncthreads();   // fw2T ready; no barriers inside the loop

    unsigned short* twave = &tbuf[wave * 16 * PT];
    const int gwave   = blockIdx.x * 4 + wave;
    const int gstride = gridDim.x * 4;

    for (int node = gwave; node < n_nodes; node += gstride) {
        const int rp0 = rp[node];
        const int rp1 = rp[node + 1];

        float accn[8];
#pragma unroll
        for (int nt = 0; nt < 8; ++nt) accn[nt] = 0.0f;

        for (int base = rp0; base < rp1; base += 16) {
            // ---- edge meta: lane handles edge m = l15 (x4 redundant) ----
            const int p = base + l15;
            const bool valid = (p < rp1);
            const int pidx = valid ? p : rp0;
            const int col = scol[pidx];
            const float dist = sdist[pidx];
            const float cut = (valid && dist <= CUTOFF)
                ? 0.5f * (__cosf(PI_F * dist * (1.0f / CUTOFF)) + 1.0f) : 0.0f;

            // broadcast to C-layout owners (m = quad*4 + r) via shfl
            int mcol[4]; float mcut[4];
#pragma unroll
            for (int r = 0; r < 4; ++r) {
                const int src = quad * 4 + r;   // lanes 0..15 hold edges 0..15
                mcol[r] = __shfl(col, src);
                mcut[r] = __shfl(cut, src);
            }

            // ---- EARLY h gather (consumed only in the epilogue) ----
            float hv[4][8];
#pragma unroll
            for (int r = 0; r < 4; ++r)
#pragma unroll
                for (int nt = 0; nt < 8; ++nt)
                    hv[r][nt] = h[mcol[r] * HIDDEN + nt * 16 + l15];

            // ---- A1 fragments: RBFs computed analytically in-register ----
            short8 a1[2];
#pragma unroll
            for (int kit = 0; kit < 2; ++kit) {
                short8 f;
#pragma unroll
                for (int j = 0; j < 8; ++j) {
                    const int k = kit * 32 + quad * 8 + j;
                    const float x = (dist - OFF_STEP * (float)k) * INV_WIDTH;
                    const float rv = (k < NUM_RBF) ? __expf(-0.5f * x * x) : 0.0f;
                    f[j] = (short)f2bf(rv);
                }
                a1[kit] = f;
            }

            // ---- layer 1 -> silu -> tbuf (bf16) ----
#pragma unroll
            for (int nt = 0; nt < 8; ++nt) {
                floatx4 c = {fb1v[nt], fb1v[nt], fb1v[nt], fb1v[nt]};
                c = __builtin_amdgcn_mfma_f32_16x16x32_bf16(a1[0], b1[0][nt], c, 0, 0, 0);
                c = __builtin_amdgcn_mfma_f32_16x16x32_bf16(a1[1], b1[1][nt], c, 0, 0, 0);
#pragma unroll
                for (int r = 0; r < 4; ++r)
                    twave[(quad * 4 + r) * PT + nt * 16 + l15] = f2bf(silu(c[r]));
            }

            // ---- A2 fragments from tbuf ----
            short8 a2[4];
#pragma unroll
            for (int kit = 0; kit < 4; ++kit)
                a2[kit] = *(const short8*)&twave[l15 * PT + kit * 32 + quad * 8];

            // ---- layer 2 + cut*h epilogue into register accumulator ----
#pragma unroll
            for (int nt = 0; nt < 8; ++nt) {
                floatx4 c = {fb2v[nt], fb2v[nt], fb2v[nt], fb2v[nt]};
#pragma unroll
                for (int kit = 0; kit < 4; ++kit) {
                    const short8 b =
                        *(const short8*)&fw2T[(nt * 16 + l15) * PK2 + kit * 32 + quad * 8];
                    c = __builtin_amdgcn_mfma_f32_16x16x32_bf16(a2[kit], b, c, 0, 0, 0);
                }
#pragma unroll
                for (int r = 0; r < 4; ++r)
                    accn[nt] += c[r] * mcut[r] * hv[r][nt];
            }
        }

        // ---- cross-quad reduction (rows live in quads) + coalesced store ----
        float sred[8];
#pragma unroll
        for (int nt = 0; nt < 8; ++nt) {
            float s = accn[nt];
            s += __shfl_xor(s, 16);
            s += __shfl_xor(s, 32);
            sred[nt] = s;
        }
        // quad q stores channels of nt = 2q, 2q+1: full wave, 64B segments
#pragma unroll
        for (int b = 0; b < 2; ++b) {
            const int nt = quad * 2 + b;
            agg[node * HIDDEN + nt * 16 + l15] = sred[nt];
        }
    }
}

// ---------------------------------------------------------------------------
// Fallback edge kernel (unsorted, atomicAdd) — used only if scratch too small.
// ---------------------------------------------------------------------------
__global__ __launch_bounds__(256) void edge_mfma_kernel(
    const float* __restrict__ h,
    const float* __restrict__ pos,
    const int* __restrict__ ei,
    const float* __restrict__ fw1,
    const float* __restrict__ fb1,
    const float* __restrict__ fw2,
    const float* __restrict__ fb2,
    float* __restrict__ agg,
    int n_nodes, int n_edges)
{
    __shared__ __attribute__((aligned(16))) unsigned short fw2T[128 * PK2];
    __shared__ __attribute__((aligned(16))) unsigned short tbuf[4 * 16 * PT];

    const int tid  = threadIdx.x;
    const int wave = tid >> 6;
    const int lane = tid & 63;
    const int l15  = lane & 15;
    const int quad = lane >> 4;

    for (int idx = tid; idx < HIDDEN * HIDDEN; idx += 256) {
        const int k = idx >> 7, n = idx & 127;
        fw2T[n * PK2 + k] = f2bf(fw2[idx]);
    }

    short8 b1[2][8];
#pragma unroll
    for (int kit = 0; kit < 2; ++kit)
#pragma unroll
        for (int nt = 0; nt < 8; ++nt) {
            short8 f;
#pragma unroll
            for (int j = 0; j < 8; ++j) {
                const int k = kit * 32 + quad * 8 + j;
                const int n = nt * 16 + l15;
                f[j] = (k < NUM_RBF) ? (short)f2bf(fw1[k * HIDDEN + n]) : (short)0;
            }
            b1[kit][nt] = f;
        }

    float fb1v[8], fb2v[8];
#pragma unroll
    for (int nt = 0; nt < 8; ++nt) {
        fb1v[nt] = fb1[nt * 16 + l15];
        fb2v[nt] = fb2[nt * 16 + l15];
    }

    __syncthreads();

    unsigned short* twave = &tbuf[wave * 16 * PT];
    const int tiles = (n_edges + 15) >> 4;

    for (int tile = blockIdx.x * 4 + wave; tile < tiles; tile += gridDim.x * 4) {
        const int e = tile * 16 + l15;
        const bool valid = (e < n_edges);
        const int eidx = valid ? e : (n_edges - 1);

        int row = min(max(ei[eidx], 0), n_nodes - 1);
        int col = min(max(ei[n_edges + eidx], 0), n_nodes - 1);
        const float dx = pos[row * 3 + 0] - pos[col * 3 + 0];
        const float dy = pos[row * 3 + 1] - pos[col * 3 + 1];
        const float dz = pos[row * 3 + 2] - pos[col * 3 + 2];
        const float dist = sqrtf(dx * dx + dy * dy + dz * dz + 1e-8f);
        const float cut = (valid && dist <= CUTOFF)
            ? 0.5f * (__cosf(PI_F * dist * (1.0f / CUTOFF)) + 1.0f) : 0.0f;

        int mrow[4], mcol[4]; float mcut[4];
#pragma unroll
        for (int r = 0; r < 4; ++r) {
            const int src = quad * 4 + r;
            mrow[r] = __shfl(row, src);
            mcol[r] = __shfl(col, src);
            mcut[r] = __shfl(cut, src);
        }

        float hv[4][8];
#pragma unroll
        for (int r = 0; r < 4; ++r)
#pragma unroll
            for (int nt = 0; nt < 8; ++nt)
                hv[r][nt] = h[mcol[r] * HIDDEN + nt * 16 + l15];

        short8 a1[2];
#pragma unroll
        for (int kit = 0; kit < 2; ++kit) {
            short8 f;
#pragma unroll
            for (int j = 0; j < 8; ++j) {
                const int k = kit * 32 + quad * 8 + j;
                const float x = (dist - OFF_STEP * (float)k) * INV_WIDTH;
                const float rv = (k < NUM_RBF) ? __expf(-0.5f * x * x) : 0.0f;
                f[j] = (short)f2bf(rv);
            }
            a1[kit] = f;
        }

#pragma unroll
        for (int nt = 0; nt < 8; ++nt) {
            floatx4 c = {fb1v[nt], fb1v[nt], fb1v[nt], fb1v[nt]};
            c = __builtin_amdgcn_mfma_f32_16x16x32_bf16(a1[0], b1[0][nt], c, 0, 0, 0);
            c = __builtin_amdgcn_mfma_f32_16x16x32_bf16(a1[1], b1[1][nt], c, 0, 0, 0);
#pragma unroll
            for (int r = 0; r < 4; ++r)
                twave[(quad * 4 + r) * PT + nt * 16 + l15] = f2bf(silu(c[r]));
        }

        short8 a2[4];
#pragma unroll
        for (int kit = 0; kit < 4; ++kit)
            a2[kit] = *(const short8*)&twave[l15 * PT + kit * 32 + quad * 8];

#pragma unroll
        for (int nt = 0; nt < 8; ++nt) {
            floatx4 c = {fb2v[nt], fb2v[nt], fb2v[nt], fb2v[nt]};
#pragma unroll
            for (int kit = 0; kit < 4; ++kit) {
                const short8 b =
                    *(const short8*)&fw2T[(nt * 16 + l15) * PK2 + kit * 32 + quad * 8];
                c = __builtin_amdgcn_mfma_f32_16x16x32_bf16(a2[kit], b, c, 0, 0, 0);
            }
            const int chan = nt * 16 + l15;
#pragma unroll
            for (int r = 0; r < 4; ++r)
                atomicAdd(&agg[mrow[r] * HIDDEN + chan], c[r] * mcut[r] * hv[r][nt]);
        }
    }
}

// ---------------------------------------------------------------------------
// Node kernel (MFMA): out = h + silu(agg@iw1+b1)@iw2+b2.
// ---------------------------------------------------------------------------
__global__ __launch_bounds__(256) void node_mfma_kernel(
    const float* __restrict__ h,
    const float* __restrict__ agg,
    const float* __restrict__ iw1,
    const float* __restrict__ ib1,
    const float* __restrict__ iw2,
    const float* __restrict__ ib2,
    float* __restrict__ out,
    int n_nodes)
{
    __shared__ __attribute__((aligned(16))) unsigned short w2T[128 * PK2];
    __shared__ __attribute__((aligned(16))) unsigned short tbuf[4 * 16 * PT];

    const int tid  = threadIdx.x;
    const int wave = tid >> 6;
    const int lane = tid & 63;
    const int l15  = lane & 15;
    const int quad = lane >> 4;

    for (int idx = tid; idx < HIDDEN * HIDDEN; idx += 256) {
        const int k = idx >> 7, n = idx & 127;
        w2T[n * PK2 + k] = f2bf(iw2[idx]);
    }

    short8 b1[4][8];
#pragma unroll
    for (int kit = 0; kit < 4; ++kit)
#pragma unroll
        for (int nt = 0; nt < 8; ++nt) {
            short8 f;
#pragma unroll
            for (int j = 0; j < 8; ++j) {
                const int k = kit * 32 + quad * 8 + j;
                f[j] = (short)f2bf(iw1[k * HIDDEN + nt * 16 + l15]);
            }
            b1[kit][nt] = f;
        }

    float ib1v[8], ib2v[8];
#pragma unroll
    for (int nt = 0; nt < 8; ++nt) {
        ib1v[nt] = ib1[nt * 16 + l15];
        ib2v[nt] = ib2[nt * 16 + l15];
    }

    __syncthreads();

    unsigned short* twave = &tbuf[wave * 16 * PT];
    const int tiles = (n_nodes + 15) >> 4;

    for (int tile = blockIdx.x * 4 + wave; tile < tiles; tile += gridDim.x * 4) {
        const int m0 = tile * 16;

        const int mA = min(m0 + l15, n_nodes - 1);
        short8 a1[4];
#pragma unroll
        for (int kit = 0; kit < 4; ++kit) {
            const float* p = &agg[mA * HIDDEN + kit * 32 + quad * 8];
            short8 f;
#pragma unroll
            for (int j = 0; j < 8; ++j) f[j] = (short)f2bf(p[j]);
            a1[kit] = f;
        }

        int mo[4]; float hres[4][8];
#pragma unroll
        for (int r = 0; r < 4; ++r) {
            mo[r] = m0 + quad * 4 + r;
            const int mc = min(mo[r], n_nodes - 1);
#pragma unroll
            for (int nt = 0; nt < 8; ++nt)
                hres[r][nt] = h[mc * HIDDEN + nt * 16 + l15];
        }

#pragma unroll
        for (int nt = 0; nt < 8; ++nt) {
            floatx4 c = {ib1v[nt], ib1v[nt], ib1v[nt], ib1v[nt]};
#pragma unroll
            for (int kit = 0; kit < 4; ++kit)
                c = __builtin_amdgcn_mfma_f32_16x16x32_bf16(a1[kit], b1[kit][nt], c, 0, 0, 0);
#pragma unroll
            for (int r = 0; r < 4; ++r)
                twave[(quad * 4 + r) * PT + nt * 16 + l15] = f2bf(silu(c[r]));
        }

        short8 a2[4];
#pragma unroll
        for (int kit = 0; kit < 4; ++kit)
            a2[kit] = *(const short8*)&twave[l15 * PT + kit * 32 + quad * 8];

#pragma unroll
        for (int nt = 0; nt < 8; ++nt) {
            floatx4 c = {ib2v[nt], ib2v[nt], ib2v[nt], ib2v[nt]};
#pragma unroll
            for (int kit = 0; kit < 4; ++kit) {
                const short8 b =
                    *(const short8*)&w2T[(nt * 16 + l15) * PK2 + kit * 32 + quad * 8];
                c = __builtin_amdgcn_mfma_f32_16x16x32_bf16(a2[kit], b, c, 0, 0, 0);
            }
            const int chan = nt * 16 + l15;
#pragma unroll
            for (int r = 0; r < 4; ++r)
                if (mo[r] < n_nodes)
                    out[mo[r] * HIDDEN + chan] = hres[r][nt] + c[r];
        }
    }
}

extern "C" void kernel_launch(void* const* d_in, const int* in_sizes, int n_in,
                              void* d_out, int out_size, void* d_ws, size_t ws_size,
                              hipStream_t stream)
{
    const float* h   = (const float*)d_in[0];
    const float* pos = (const float*)d_in[1];
    const int*   ei  = (const int*)d_in[2];
    const float* fw1 = (const float*)d_in[3];
    const float* fb1 = (const float*)d_in[4];
    const float* fw2 = (const float*)d_in[5];
    const float* fb2 = (const float*)d_in[6];
    const float* iw1 = (const float*)d_in[7];
    const float* ib1 = (const float*)d_in[8];
    const float* iw2 = (const float*)d_in[9];
    const float* ib2 = (const float*)d_in[10];
    float* out = (float*)d_out;

    const int n_nodes = in_sizes[0] / HIDDEN;
    const int n_edges = in_sizes[2] / 2;
    const int nscan   = (n_nodes + 255) >> 8;   // scanA blocks (<=256 required)

    const size_t need = (size_t)n_nodes * HIDDEN * sizeof(float);
    const bool use_ws = (d_ws != nullptr) && (ws_size >= need);

    // scratch layout in d_out (ints): cnt[n] cursor[n] btot[256] boff[256]
    // rp[n+1] wcur[n] scol[E] sdist[E]
    const size_t scratch_ints =
        (size_t)4 * n_nodes + 513 + (size_t)2 * n_edges;
    const bool can_sort = use_ws && nscan <= 256 &&
                          ((size_t)out_size >= scratch_ints);

    if (can_sort) {
        float* agg    = (float*)d_ws;
        int*   base   = (int*)d_out;
        int*   cnt    = base;
        int*   cursor = base + n_nodes;
        int*   btot   = base + 2 * n_nodes;
        int*   boff   = btot + 256;
        int*   rp     = boff + 256;                 // n_nodes + 1
        int*   wcur   = rp + n_nodes + 1;
        int*   scol   = wcur + n_nodes;
        float* sdist  = (float*)(scol + n_edges);

        hipMemsetAsync(cnt, 0, (size_t)n_nodes * sizeof(int), stream);

        hist_kernel<<<1024, 256, 0, stream>>>(ei, cnt, n_nodes, n_edges);
        scanA_kernel<<<nscan, 256, 0, stream>>>(cnt, cursor, btot, n_nodes);
        scanB_kernel<<<1, 256, 0, stream>>>(btot, boff, nscan);
        finalize_kernel<<<(n_nodes + 256) / 256, 256, 0, stream>>>(
            cursor, boff, rp, wcur, n_nodes, n_edges);
        scatter_kernel<<<1024, 256, 0, stream>>>(ei, pos, wcur, scol, sdist,
                                                 n_nodes, n_edges);

        edge_mfma_csr_kernel<<<1536, 256, 0, stream>>>(
            h, rp, scol, sdist, fw1, fb1, fw2, fb2, agg, n_nodes);

        node_mfma_kernel<<<256, 256, 0, stream>>>(h, agg, iw1, ib1, iw2, ib2,
                                                  out, n_nodes);
    } else {
        float* agg = use_ws ? (float*)d_ws : out;
        hipMemsetAsync(agg, 0, need, stream);
        edge_mfma_kernel<<<1536, 256, 0, stream>>>(
            h, pos, ei, fw1, fb1, fw2, fb2, agg, n_nodes, n_edges);
        node_mfma_kernel<<<256, 256, 0, stream>>>(h, agg, iw1, ib1, iw2, ib2,
                                                  out, n_nodes);
    }
}

// Round 9
// 437.927 us; speedup vs baseline: 1.5723x; 1.5723x over previous
//
#include <hip/hip_runtime.h>
#include <hip/hip_bf16.h>

#define HIDDEN  128
#define NUM_RBF 50
#define CUTOFF  5.0f
#define INV_WIDTH (49.0f / 5.0f)
#define OFF_STEP  (5.0f / 49.0f)
#define PI_F 3.14159265358979f

// LDS row stride (halfs). 136 = 128+8: rows 16B-aligned (272 B) and fragment
// reads land 2-way bank-aliased (free per m136).
#define PK2 136
#define PT  136

typedef __attribute__((ext_vector_type(8))) short short8;   // 8 bf16 (4 VGPR)
typedef __attribute__((ext_vector_type(4))) float floatx4;  // MFMA acc

__device__ __forceinline__ unsigned short f2bf(float x) {
    union { float f; unsigned int u; } v; v.f = x;
    return (unsigned short)((v.u + 0x7fff + ((v.u >> 16) & 1)) >> 16);  // RNE
}

__device__ __forceinline__ float silu(float x) {
    return x / (1.0f + __expf(-x));
}

// ---------------------------------------------------------------------------
// Counting-sort pipeline (scratch lives in d_out; node kernel overwrites d_out
// only at the very end). Hierarchical scan: local 256-bin scans + top scan.
// ---------------------------------------------------------------------------
__global__ void hist_kernel(const int* __restrict__ ei, int* __restrict__ cnt,
                            int n_nodes, int n_edges)
{
    for (int e = blockIdx.x * blockDim.x + threadIdx.x; e < n_edges;
         e += gridDim.x * blockDim.x) {
        const int r = min(max(ei[e], 0), n_nodes - 1);
        atomicAdd(&cnt[r], 1);
    }
}

// Local exclusive scan over 256-bin segments; emits per-segment totals.
__global__ __launch_bounds__(256) void scanA_kernel(const int* __restrict__ cnt,
                                                    int* __restrict__ cursor,
                                                    int* __restrict__ btot,
                                                    int nb)
{
    __shared__ int s[256];
    const int t = threadIdx.x;
    const int i = blockIdx.x * 256 + t;
    const int v = (i < nb) ? cnt[i] : 0;
    s[t] = v;
    __syncthreads();
#pragma unroll
    for (int off = 1; off < 256; off <<= 1) {
        const int u = (t >= off) ? s[t - off] : 0;
        __syncthreads();
        s[t] += u;
        __syncthreads();
    }
    if (i < nb) cursor[i] = s[t] - v;           // local exclusive prefix
    if (t == 255) btot[blockIdx.x] = s[255];    // segment total
}

// Single small block: exclusive scan of segment totals.
__global__ __launch_bounds__(256) void scanB_kernel(const int* __restrict__ btot,
                                                    int* __restrict__ boff,
                                                    int nblk)
{
    __shared__ int s[256];
    const int t = threadIdx.x;
    const int v = (t < nblk) ? btot[t] : 0;
    s[t] = v;
    __syncthreads();
#pragma unroll
    for (int off = 1; off < 256; off <<= 1) {
        const int u = (t >= off) ? s[t - off] : 0;
        __syncthreads();
        s[t] += u;
        __syncthreads();
    }
    if (t < nblk) boff[t] = s[t] - v;
}

__global__ void scatter_kernel(const int* __restrict__ ei,
                               const float* __restrict__ pos,
                               int* __restrict__ cursor,
                               const int* __restrict__ boff,
                               int2* __restrict__ rc,
                               float* __restrict__ sdist,
                               int n_nodes, int n_edges)
{
    for (int e = blockIdx.x * blockDim.x + threadIdx.x; e < n_edges;
         e += gridDim.x * blockDim.x) {
        const int r = min(max(ei[e], 0), n_nodes - 1);
        const int c = min(max(ei[n_edges + e], 0), n_nodes - 1);
        const float dx = pos[r * 3 + 0] - pos[c * 3 + 0];
        const float dy = pos[r * 3 + 1] - pos[c * 3 + 1];
        const float dz = pos[r * 3 + 2] - pos[c * 3 + 2];
        const float dist = sqrtf(dx * dx + dy * dy + dz * dz + 1e-8f);
        const int p = boff[r >> 8] + atomicAdd(&cursor[r], 1);
        rc[p] = make_int2(r, c);
        sdist[p] = dist;
    }
}

// ---------------------------------------------------------------------------
// Edge kernel: 256 thr = 4 waves, each wave owns 16-edge tiles (grid-stride).
// fw2 staged once/block in LDS; fw1 frags + biases in registers.
// SORTED path: next-tile meta prefetched into registers; messages staged bf16
// in wave-private LDS; segmented walk with ballot boundary mask (uniform
// branches, no bpermute chain) pre-reduces equal-row runs.
// ---------------------------------------------------------------------------
template<bool SORTED>
__global__ __launch_bounds__(256) void edge_mfma_kernel(
    const float* __restrict__ h,
    const float* __restrict__ pos,
    const int* __restrict__ ei,
    const int2* __restrict__ rc,
    const float* __restrict__ sdist,
    const float* __restrict__ fw1,
    const float* __restrict__ fb1,
    const float* __restrict__ fw2,
    const float* __restrict__ fb2,
    float* __restrict__ agg,
    int n_nodes, int n_edges)
{
    __shared__ __attribute__((aligned(16))) unsigned short fw2T[128 * PK2];
    __shared__ __attribute__((aligned(16))) unsigned short tbuf[4 * 16 * PT];
    __shared__ int s_rowbuf[4][16];

    const int tid  = threadIdx.x;
    const int wave = tid >> 6;
    const int lane = tid & 63;
    const int l15  = lane & 15;
    const int quad = lane >> 4;

    // stage fw2 transposed (bf16): fw2T[n][k] = fw2[k][n]
    for (int idx = tid; idx < HIDDEN * HIDDEN; idx += 256) {
        const int k = idx >> 7, n = idx & 127;
        fw2T[n * PK2 + k] = f2bf(fw2[idx]);
    }

    // fw1 B-fragments in registers (zero rows k>=50)
    short8 b1[2][8];
#pragma unroll
    for (int kit = 0; kit < 2; ++kit)
#pragma unroll
        for (int nt = 0; nt < 8; ++nt) {
            short8 f;
#pragma unroll
            for (int j = 0; j < 8; ++j) {
                const int k = kit * 32 + quad * 8 + j;
                const int n = nt * 16 + l15;
                f[j] = (k < NUM_RBF) ? (short)f2bf(fw1[k * HIDDEN + n]) : (short)0;
            }
            b1[kit][nt] = f;
        }

    float fb1v[8], fb2v[8];
#pragma unroll
    for (int nt = 0; nt < 8; ++nt) {
        fb1v[nt] = fb1[nt * 16 + l15];
        fb2v[nt] = fb2[nt * 16 + l15];
    }

    __syncthreads();   // fw2T ready; no barriers inside the loop

    unsigned short* twave = &tbuf[wave * 16 * PT];
    const int tiles = (n_edges + 15) >> 4;
    const int tstride = gridDim.x * 4;
    int tile = blockIdx.x * 4 + wave;

    // ---- prefetch first tile's meta (sorted path) ----
    int2  nrc   = make_int2(0, 0);
    float ndist = 0.0f;
    bool  nval  = false;
    if (SORTED && tile < tiles) {
        const int e = tile * 16 + l15;
        nval = (e < n_edges);
        const int idx = min(e, n_edges - 1);
        nrc = rc[idx];
        ndist = sdist[idx];
    }

    for (; tile < tiles; tile += tstride) {
        // ---- edge meta: lane handles edge m = l15 (x4 redundant) ----
        int row, col; float dist; bool valid;
        if (SORTED) {
            row = nrc.x; col = nrc.y; dist = ndist; valid = nval;
            // prefetch NEXT tile's meta; consumed one iteration later
            const int tn = tile + tstride;
            if (tn < tiles) {
                const int e = tn * 16 + l15;
                nval = (e < n_edges);
                const int idx = min(e, n_edges - 1);
                nrc = rc[idx];
                ndist = sdist[idx];
            }
        } else {
            const int e = tile * 16 + l15;
            valid = (e < n_edges);
            const int eidx = valid ? e : (n_edges - 1);
            row = min(max(ei[eidx], 0), n_nodes - 1);
            col = min(max(ei[n_edges + eidx], 0), n_nodes - 1);
            const float dx = pos[row * 3 + 0] - pos[col * 3 + 0];
            const float dy = pos[row * 3 + 1] - pos[col * 3 + 1];
            const float dz = pos[row * 3 + 2] - pos[col * 3 + 2];
            dist = sqrtf(dx * dx + dy * dy + dz * dz + 1e-8f);
        }
        const float cut = (valid && dist <= CUTOFF)
            ? 0.5f * (__cosf(PI_F * dist * (1.0f / CUTOFF)) + 1.0f) : 0.0f;

        // broadcast to C-layout owners (m = quad*4 + r) via shfl
        int mrow[4], mcol[4]; float mcut[4];
#pragma unroll
        for (int r = 0; r < 4; ++r) {
            const int src = quad * 4 + r;      // lanes 0..15 hold edges 0..15
            if (!SORTED) mrow[r] = __shfl(row, src);
            mcol[r] = __shfl(col, src);
            mcut[r] = __shfl(cut, src);
        }

        // ---- EARLY h gather (consumed only in the epilogue) ----
        float hv[4][8];
#pragma unroll
        for (int r = 0; r < 4; ++r)
#pragma unroll
            for (int nt = 0; nt < 8; ++nt)
                hv[r][nt] = h[mcol[r] * HIDDEN + nt * 16 + l15];

        // ---- A1 fragments: RBFs computed analytically in-register ----
        short8 a1[2];
#pragma unroll
        for (int kit = 0; kit < 2; ++kit) {
            short8 f;
#pragma unroll
            for (int j = 0; j < 8; ++j) {
                const int k = kit * 32 + quad * 8 + j;
                const float x = (dist - OFF_STEP * (float)k) * INV_WIDTH;
                const float rv = (k < NUM_RBF) ? __expf(-0.5f * x * x) : 0.0f;
                f[j] = (short)f2bf(rv);
            }
            a1[kit] = f;
        }

        // ---- layer 1 -> silu -> tbuf (bf16) ----
#pragma unroll
        for (int nt = 0; nt < 8; ++nt) {
            floatx4 c = {fb1v[nt], fb1v[nt], fb1v[nt], fb1v[nt]};
            c = __builtin_amdgcn_mfma_f32_16x16x32_bf16(a1[0], b1[0][nt], c, 0, 0, 0);
            c = __builtin_amdgcn_mfma_f32_16x16x32_bf16(a1[1], b1[1][nt], c, 0, 0, 0);
#pragma unroll
            for (int r = 0; r < 4; ++r)
                twave[(quad * 4 + r) * PT + nt * 16 + l15] = f2bf(silu(c[r]));
        }

        // ---- A2 fragments from tbuf (tbuf free for reuse afterwards) ----
        short8 a2[4];
#pragma unroll
        for (int kit = 0; kit < 4; ++kit)
            a2[kit] = *(const short8*)&twave[l15 * PT + kit * 32 + quad * 8];

        // ---- layer 2 + cutoff*h epilogue ----
#pragma unroll
        for (int nt = 0; nt < 8; ++nt) {
            floatx4 c = {fb2v[nt], fb2v[nt], fb2v[nt], fb2v[nt]};
#pragma unroll
            for (int kit = 0; kit < 4; ++kit) {
                const short8 b =
                    *(const short8*)&fw2T[(nt * 16 + l15) * PK2 + kit * 32 + quad * 8];
                c = __builtin_amdgcn_mfma_f32_16x16x32_bf16(a2[kit], b, c, 0, 0, 0);
            }
            const int chan = nt * 16 + l15;
#pragma unroll
            for (int r = 0; r < 4; ++r) {
                const float val = c[r] * mcut[r] * hv[r][nt];
                if (SORTED) {
                    // stage message (bf16) for the segmented walk
                    twave[(quad * 4 + r) * PT + chan] = f2bf(val);
                } else {
                    atomicAdd(&agg[mrow[r] * HIDDEN + chan], val);
                }
            }
        }

        if (SORTED) {
            // ---- segmented walk: rows sorted within tile; uniform-branch
            // flush at run boundaries (ballot mask), LDS broadcast row lookup.
            if (lane < 16) s_rowbuf[wave][l15] = row;
            const int pr = __shfl(row, (l15 > 0) ? (l15 - 1) : 0);
            const unsigned long long bal =
                __ballot((l15 > 0) && (row != pr));
            const unsigned int mask = (unsigned int)bal & 0xFFFFu;

            const int c0 = lane * 2;          // this lane owns chans c0, c0+1
            float acc0 = 0.0f, acc1 = 0.0f;
            int prow = s_rowbuf[wave][0];
#pragma unroll
            for (int i = 0; i < 16; ++i) {
                const unsigned int bits =
                    *(const unsigned int*)&twave[i * PT + c0];
                union { unsigned int u; float f; } lo, hi;
                lo.u = bits << 16;            // chan c0
                hi.u = bits & 0xffff0000u;    // chan c0+1
                if (mask & (1u << i)) {       // wave-uniform branch
                    atomicAdd(&agg[prow * HIDDEN + c0],     acc0);
                    atomicAdd(&agg[prow * HIDDEN + c0 + 1], acc1);
                    acc0 = 0.0f; acc1 = 0.0f;
                    prow = s_rowbuf[wave][i];
                }
                acc0 += lo.f; acc1 += hi.f;
            }
            atomicAdd(&agg[prow * HIDDEN + c0],     acc0);
            atomicAdd(&agg[prow * HIDDEN + c0 + 1], acc1);
        }
    }
}

// ---------------------------------------------------------------------------
// Node kernel (MFMA): out = h + silu(agg@iw1+b1)@iw2+b2.
// 256 blocks: weight staging amortized over ~3 tiles/wave.
// ---------------------------------------------------------------------------
__global__ __launch_bounds__(256) void node_mfma_kernel(
    const float* __restrict__ h,
    const float* __restrict__ agg,
    const float* __restrict__ iw1,
    const float* __restrict__ ib1,
    const float* __restrict__ iw2,
    const float* __restrict__ ib2,
    float* __restrict__ out,
    int n_nodes)
{
    __shared__ __attribute__((aligned(16))) unsigned short w2T[128 * PK2];
    __shared__ __attribute__((aligned(16))) unsigned short tbuf[4 * 16 * PT];

    const int tid  = threadIdx.x;
    const int wave = tid >> 6;
    const int lane = tid & 63;
    const int l15  = lane & 15;
    const int quad = lane >> 4;

    for (int idx = tid; idx < HIDDEN * HIDDEN; idx += 256) {
        const int k = idx >> 7, n = idx & 127;
        w2T[n * PK2 + k] = f2bf(iw2[idx]);
    }

    short8 b1[4][8];
#pragma unroll
    for (int kit = 0; kit < 4; ++kit)
#pragma unroll
        for (int nt = 0; nt < 8; ++nt) {
            short8 f;
#pragma unroll
            for (int j = 0; j < 8; ++j) {
                const int k = kit * 32 + quad * 8 + j;
                f[j] = (short)f2bf(iw1[k * HIDDEN + nt * 16 + l15]);
            }
            b1[kit][nt] = f;
        }

    float ib1v[8], ib2v[8];
#pragma unroll
    for (int nt = 0; nt < 8; ++nt) {
        ib1v[nt] = ib1[nt * 16 + l15];
        ib2v[nt] = ib2[nt * 16 + l15];
    }

    __syncthreads();

    unsigned short* twave = &tbuf[wave * 16 * PT];
    const int tiles = (n_nodes + 15) >> 4;

    for (int tile = blockIdx.x * 4 + wave; tile < tiles; tile += gridDim.x * 4) {
        const int m0 = tile * 16;

        const int mA = min(m0 + l15, n_nodes - 1);
        short8 a1[4];
#pragma unroll
        for (int kit = 0; kit < 4; ++kit) {
            const float* p = &agg[mA * HIDDEN + kit * 32 + quad * 8];
            short8 f;
#pragma unroll
            for (int j = 0; j < 8; ++j) f[j] = (short)f2bf(p[j]);
            a1[kit] = f;
        }

        int mo[4]; float hres[4][8];
#pragma unroll
        for (int r = 0; r < 4; ++r) {
            mo[r] = m0 + quad * 4 + r;
            const int mc = min(mo[r], n_nodes - 1);
#pragma unroll
            for (int nt = 0; nt < 8; ++nt)
                hres[r][nt] = h[mc * HIDDEN + nt * 16 + l15];
        }

#pragma unroll
        for (int nt = 0; nt < 8; ++nt) {
            floatx4 c = {ib1v[nt], ib1v[nt], ib1v[nt], ib1v[nt]};
#pragma unroll
            for (int kit = 0; kit < 4; ++kit)
                c = __builtin_amdgcn_mfma_f32_16x16x32_bf16(a1[kit], b1[kit][nt], c, 0, 0, 0);
#pragma unroll
            for (int r = 0; r < 4; ++r)
                twave[(quad * 4 + r) * PT + nt * 16 + l15] = f2bf(silu(c[r]));
        }

        short8 a2[4];
#pragma unroll
        for (int kit = 0; kit < 4; ++kit)
            a2[kit] = *(const short8*)&twave[l15 * PT + kit * 32 + quad * 8];

#pragma unroll
        for (int nt = 0; nt < 8; ++nt) {
            floatx4 c = {ib2v[nt], ib2v[nt], ib2v[nt], ib2v[nt]};
#pragma unroll
            for (int kit = 0; kit < 4; ++kit) {
                const short8 b =
                    *(const short8*)&w2T[(nt * 16 + l15) * PK2 + kit * 32 + quad * 8];
                c = __builtin_amdgcn_mfma_f32_16x16x32_bf16(a2[kit], b, c, 0, 0, 0);
            }
            const int chan = nt * 16 + l15;
#pragma unroll
            for (int r = 0; r < 4; ++r)
                if (mo[r] < n_nodes)
                    out[mo[r] * HIDDEN + chan] = hres[r][nt] + c[r];
        }
    }
}

extern "C" void kernel_launch(void* const* d_in, const int* in_sizes, int n_in,
                              void* d_out, int out_size, void* d_ws, size_t ws_size,
                              hipStream_t stream)
{
    const float* h   = (const float*)d_in[0];
    const float* pos = (const float*)d_in[1];
    const int*   ei  = (const int*)d_in[2];
    const float* fw1 = (const float*)d_in[3];
    const float* fb1 = (const float*)d_in[4];
    const float* fw2 = (const float*)d_in[5];
    const float* fb2 = (const float*)d_in[6];
    const float* iw1 = (const float*)d_in[7];
    const float* ib1 = (const float*)d_in[8];
    const float* iw2 = (const float*)d_in[9];
    const float* ib2 = (const float*)d_in[10];
    float* out = (float*)d_out;

    const int n_nodes = in_sizes[0] / HIDDEN;
    const int n_edges = in_sizes[2] / 2;
    const int nscan   = (n_nodes + 255) >> 8;   // scanA blocks (<=256 required)

    const size_t need = (size_t)n_nodes * HIDDEN * sizeof(float);
    const bool use_ws = (d_ws != nullptr) && (ws_size >= need);

    // sort scratch layout in d_out (ints): cnt[nb] cursor[nb] btot[256]
    // boff[256] rc[2E] sdist[E]
    const size_t scratch_ints = (size_t)2 * n_nodes + 512 + (size_t)3 * n_edges;
    const bool can_sort = use_ws && nscan <= 256 &&
                          ((size_t)out_size >= scratch_ints);

    if (can_sort) {
        float* agg    = (float*)d_ws;
        int*   base   = (int*)d_out;
        int*   cnt    = base;
        int*   cursor = base + n_nodes;
        int*   btot   = base + 2 * n_nodes;
        int*   boff   = btot + 256;
        int2*  rc     = (int2*)(boff + 256);
        float* sdist  = (float*)(boff + 256 + 2 * n_edges);

        hipMemsetAsync(cnt, 0, (size_t)n_nodes * sizeof(int), stream);
        hipMemsetAsync(agg, 0, need, stream);

        hist_kernel<<<1024, 256, 0, stream>>>(ei, cnt, n_nodes, n_edges);
        scanA_kernel<<<nscan, 256, 0, stream>>>(cnt, cursor, btot, n_nodes);
        scanB_kernel<<<1, 256, 0, stream>>>(btot, boff, nscan);
        scatter_kernel<<<1024, 256, 0, stream>>>(ei, pos, cursor, boff,
                                                 rc, sdist, n_nodes, n_edges);

        edge_mfma_kernel<true><<<1536, 256, 0, stream>>>(
            h, pos, ei, rc, sdist,
            fw1, fb1, fw2, fb2, agg, n_nodes, n_edges);

        node_mfma_kernel<<<256, 256, 0, stream>>>(h, agg, iw1, ib1, iw2, ib2,
                                                  out, n_nodes);
    } else {
        float* agg = use_ws ? (float*)d_ws : out;
        hipMemsetAsync(agg, 0, need, stream);
        edge_mfma_kernel<false><<<1536, 256, 0, stream>>>(
            h, pos, ei, nullptr, nullptr,
            fw1, fb1, fw2, fb2, agg, n_nodes, n_edges);
        node_mfma_kernel<<<256, 256, 0, stream>>>(h, agg, iw1, ib1, iw2, ib2,
                                                  out, n_nodes);
    }
}

// Round 10
// 431.820 us; speedup vs baseline: 1.5945x; 1.0141x over previous
//
#include <hip/hip_runtime.h>
#include <hip/hip_bf16.h>

#define HIDDEN  128
#define NUM_RBF 50
#define CUTOFF  5.0f
#define INV_WIDTH (49.0f / 5.0f)
#define OFF_STEP  (5.0f / 49.0f)
#define PI_F 3.14159265358979f

// LDS row stride (halfs). 136 = 128+8: rows 16B-aligned (272 B) and fragment
// reads land 2-way bank-aliased (free per m136).
#define PK2 136
#define PT  136

typedef __attribute__((ext_vector_type(8))) short short8;   // 8 bf16 (4 VGPR)
typedef __attribute__((ext_vector_type(4))) float floatx4;  // MFMA acc

// round-half-up bf16 conversion: 2 VALU ops (was 5-op RNE; extra error <= 1/2
// ULP on staged intermediates only — absmax margin 0.031 vs 0.108 threshold).
__device__ __forceinline__ unsigned short f2bf(float x) {
    union { float f; unsigned int u; } v; v.f = x;
    return (unsigned short)((v.u + 0x8000u) >> 16);
}

__device__ __forceinline__ float silu(float x) {
    return x / (1.0f + __expf(-x));
}

// ---------------------------------------------------------------------------
// Counting-sort pipeline (scratch lives in d_out; node kernel overwrites d_out
// only at the very end). Hierarchical scan: local 256-bin scans + top scan.
// ---------------------------------------------------------------------------
__global__ void hist_kernel(const int* __restrict__ ei, int* __restrict__ cnt,
                            int n_nodes, int n_edges)
{
    for (int e = blockIdx.x * blockDim.x + threadIdx.x; e < n_edges;
         e += gridDim.x * blockDim.x) {
        const int r = min(max(ei[e], 0), n_nodes - 1);
        atomicAdd(&cnt[r], 1);
    }
}

// Local exclusive scan over 256-bin segments; emits per-segment totals.
__global__ __launch_bounds__(256) void scanA_kernel(const int* __restrict__ cnt,
                                                    int* __restrict__ cursor,
                                                    int* __restrict__ btot,
                                                    int nb)
{
    __shared__ int s[256];
    const int t = threadIdx.x;
    const int i = blockIdx.x * 256 + t;
    const int v = (i < nb) ? cnt[i] : 0;
    s[t] = v;
    __syncthreads();
#pragma unroll
    for (int off = 1; off < 256; off <<= 1) {
        const int u = (t >= off) ? s[t - off] : 0;
        __syncthreads();
        s[t] += u;
        __syncthreads();
    }
    if (i < nb) cursor[i] = s[t] - v;           // local exclusive prefix
    if (t == 255) btot[blockIdx.x] = s[255];    // segment total
}

// Single small block: exclusive scan of segment totals.
__global__ __launch_bounds__(256) void scanB_kernel(const int* __restrict__ btot,
                                                    int* __restrict__ boff,
                                                    int nblk)
{
    __shared__ int s[256];
    const int t = threadIdx.x;
    const int v = (t < nblk) ? btot[t] : 0;
    s[t] = v;
    __syncthreads();
#pragma unroll
    for (int off = 1; off < 256; off <<= 1) {
        const int u = (t >= off) ? s[t - off] : 0;
        __syncthreads();
        s[t] += u;
        __syncthreads();
    }
    if (t < nblk) boff[t] = s[t] - v;
}

__global__ void scatter_kernel(const int* __restrict__ ei,
                               const float* __restrict__ pos,
                               int* __restrict__ cursor,
                               const int* __restrict__ boff,
                               int2* __restrict__ rc,
                               float* __restrict__ sdist,
                               int n_nodes, int n_edges)
{
    for (int e = blockIdx.x * blockDim.x + threadIdx.x; e < n_edges;
         e += gridDim.x * blockDim.x) {
        const int r = min(max(ei[e], 0), n_nodes - 1);
        const int c = min(max(ei[n_edges + e], 0), n_nodes - 1);
        const float dx = pos[r * 3 + 0] - pos[c * 3 + 0];
        const float dy = pos[r * 3 + 1] - pos[c * 3 + 1];
        const float dz = pos[r * 3 + 2] - pos[c * 3 + 2];
        const float dist = sqrtf(dx * dx + dy * dy + dz * dz + 1e-8f);
        const int p = boff[r >> 8] + atomicAdd(&cursor[r], 1);
        rc[p] = make_int2(r, c);
        sdist[p] = dist;
    }
}

// ---------------------------------------------------------------------------
// Edge kernel: 256 thr = 4 waves, each wave owns 16-edge tiles (grid-stride).
// fw2 staged once/block in LDS; fw1 frags + biases in registers.
// SORTED path: next-tile meta prefetched into registers; messages staged bf16
// in wave-private LDS; segmented walk with ballot boundary mask (uniform
// branches) pre-reduces equal-row runs.
// ---------------------------------------------------------------------------
template<bool SORTED>
__global__ __launch_bounds__(256) void edge_mfma_kernel(
    const float* __restrict__ h,
    const float* __restrict__ pos,
    const int* __restrict__ ei,
    const int2* __restrict__ rc,
    const float* __restrict__ sdist,
    const float* __restrict__ fw1,
    const float* __restrict__ fb1,
    const float* __restrict__ fw2,
    const float* __restrict__ fb2,
    float* __restrict__ agg,
    int n_nodes, int n_edges)
{
    __shared__ __attribute__((aligned(16))) unsigned short fw2T[128 * PK2];
    __shared__ __attribute__((aligned(16))) unsigned short tbuf[4 * 16 * PT];
    __shared__ int s_rowbuf[4][16];

    const int tid  = threadIdx.x;
    const int wave = tid >> 6;
    const int lane = tid & 63;
    const int l15  = lane & 15;
    const int quad = lane >> 4;

    // stage fw2 transposed (bf16): fw2T[n][k] = fw2[k][n]
    for (int idx = tid; idx < HIDDEN * HIDDEN; idx += 256) {
        const int k = idx >> 7, n = idx & 127;
        fw2T[n * PK2 + k] = f2bf(fw2[idx]);
    }

    // fw1 B-fragments in registers (zero rows k>=50)
    short8 b1[2][8];
#pragma unroll
    for (int kit = 0; kit < 2; ++kit)
#pragma unroll
        for (int nt = 0; nt < 8; ++nt) {
            short8 f;
#pragma unroll
            for (int j = 0; j < 8; ++j) {
                const int k = kit * 32 + quad * 8 + j;
                const int n = nt * 16 + l15;
                f[j] = (k < NUM_RBF) ? (short)f2bf(fw1[k * HIDDEN + n]) : (short)0;
            }
            b1[kit][nt] = f;
        }

    float fb1v[8], fb2v[8];
#pragma unroll
    for (int nt = 0; nt < 8; ++nt) {
        fb1v[nt] = fb1[nt * 16 + l15];
        fb2v[nt] = fb2[nt * 16 + l15];
    }

    __syncthreads();   // fw2T ready; no barriers inside the loop

    unsigned short* twave = &tbuf[wave * 16 * PT];
    const int tiles = (n_edges + 15) >> 4;
    const int tstride = gridDim.x * 4;
    int tile = blockIdx.x * 4 + wave;

    // ---- prefetch first tile's meta (sorted path) ----
    int2  nrc   = make_int2(0, 0);
    float ndist = 0.0f;
    bool  nval  = false;
    if (SORTED && tile < tiles) {
        const int e = tile * 16 + l15;
        nval = (e < n_edges);
        const int idx = min(e, n_edges - 1);
        nrc = rc[idx];
        ndist = sdist[idx];
    }

    for (; tile < tiles; tile += tstride) {
        // ---- edge meta: lane handles edge m = l15 (x4 redundant) ----
        int row, col; float dist; bool valid;
        if (SORTED) {
            row = nrc.x; col = nrc.y; dist = ndist; valid = nval;
            // prefetch NEXT tile's meta; consumed one iteration later
            const int tn = tile + tstride;
            if (tn < tiles) {
                const int e = tn * 16 + l15;
                nval = (e < n_edges);
                const int idx = min(e, n_edges - 1);
                nrc = rc[idx];
                ndist = sdist[idx];
            }
        } else {
            const int e = tile * 16 + l15;
            valid = (e < n_edges);
            const int eidx = valid ? e : (n_edges - 1);
            row = min(max(ei[eidx], 0), n_nodes - 1);
            col = min(max(ei[n_edges + eidx], 0), n_nodes - 1);
            const float dx = pos[row * 3 + 0] - pos[col * 3 + 0];
            const float dy = pos[row * 3 + 1] - pos[col * 3 + 1];
            const float dz = pos[row * 3 + 2] - pos[col * 3 + 2];
            dist = sqrtf(dx * dx + dy * dy + dz * dz + 1e-8f);
        }
        const float cut = (valid && dist <= CUTOFF)
            ? 0.5f * (__cosf(PI_F * dist * (1.0f / CUTOFF)) + 1.0f) : 0.0f;

        // broadcast to C-layout owners (m = quad*4 + r) via shfl
        int mrow[4], mcol[4]; float mcut[4];
#pragma unroll
        for (int r = 0; r < 4; ++r) {
            const int src = quad * 4 + r;      // lanes 0..15 hold edges 0..15
            if (!SORTED) mrow[r] = __shfl(row, src);
            mcol[r] = __shfl(col, src);
            mcut[r] = __shfl(cut, src);
        }

        // ---- EARLY h gather (consumed only in the epilogue) ----
        float hv[4][8];
#pragma unroll
        for (int r = 0; r < 4; ++r)
#pragma unroll
            for (int nt = 0; nt < 8; ++nt)
                hv[r][nt] = h[mcol[r] * HIDDEN + nt * 16 + l15];

        // ---- A1 fragments: RBFs computed analytically in-register ----
        short8 a1[2];
#pragma unroll
        for (int kit = 0; kit < 2; ++kit) {
            short8 f;
#pragma unroll
            for (int j = 0; j < 8; ++j) {
                const int k = kit * 32 + quad * 8 + j;
                const float x = (dist - OFF_STEP * (float)k) * INV_WIDTH;
                const float rv = (k < NUM_RBF) ? __expf(-0.5f * x * x) : 0.0f;
                f[j] = (short)f2bf(rv);
            }
            a1[kit] = f;
        }

        // ---- layer 1 -> silu -> tbuf (bf16) ----
#pragma unroll
        for (int nt = 0; nt < 8; ++nt) {
            floatx4 c = {fb1v[nt], fb1v[nt], fb1v[nt], fb1v[nt]};
            c = __builtin_amdgcn_mfma_f32_16x16x32_bf16(a1[0], b1[0][nt], c, 0, 0, 0);
            c = __builtin_amdgcn_mfma_f32_16x16x32_bf16(a1[1], b1[1][nt], c, 0, 0, 0);
#pragma unroll
            for (int r = 0; r < 4; ++r)
                twave[(quad * 4 + r) * PT + nt * 16 + l15] = f2bf(silu(c[r]));
        }

        // ---- A2 fragments from tbuf (tbuf free for reuse afterwards) ----
        short8 a2[4];
#pragma unroll
        for (int kit = 0; kit < 4; ++kit)
            a2[kit] = *(const short8*)&twave[l15 * PT + kit * 32 + quad * 8];

        // ---- layer 2 + cutoff*h epilogue ----
#pragma unroll
        for (int nt = 0; nt < 8; ++nt) {
            floatx4 c = {fb2v[nt], fb2v[nt], fb2v[nt], fb2v[nt]};
#pragma unroll
            for (int kit = 0; kit < 4; ++kit) {
                const short8 b =
                    *(const short8*)&fw2T[(nt * 16 + l15) * PK2 + kit * 32 + quad * 8];
                c = __builtin_amdgcn_mfma_f32_16x16x32_bf16(a2[kit], b, c, 0, 0, 0);
            }
            const int chan = nt * 16 + l15;
#pragma unroll
            for (int r = 0; r < 4; ++r) {
                const float val = c[r] * mcut[r] * hv[r][nt];
                if (SORTED) {
                    // stage message (bf16) for the segmented walk
                    twave[(quad * 4 + r) * PT + chan] = f2bf(val);
                } else {
                    atomicAdd(&agg[mrow[r] * HIDDEN + chan], val);
                }
            }
        }

        if (SORTED) {
            // ---- segmented walk: rows sorted within tile; uniform-branch
            // flush at run boundaries (ballot mask), LDS broadcast row lookup.
            if (lane < 16) s_rowbuf[wave][l15] = row;
            const int pr = __shfl(row, (l15 > 0) ? (l15 - 1) : 0);
            const unsigned long long bal =
                __ballot((l15 > 0) && (row != pr));
            const unsigned int mask = (unsigned int)bal & 0xFFFFu;

            const int c0 = lane * 2;          // this lane owns chans c0, c0+1
            float acc0 = 0.0f, acc1 = 0.0f;
            int prow = s_rowbuf[wave][0];
#pragma unroll
            for (int i = 0; i < 16; ++i) {
                const unsigned int bits =
                    *(const unsigned int*)&twave[i * PT + c0];
                union { unsigned int u; float f; } lo, hi;
                lo.u = bits << 16;            // chan c0
                hi.u = bits & 0xffff0000u;    // chan c0+1
                if (mask & (1u << i)) {       // wave-uniform branch
                    atomicAdd(&agg[prow * HIDDEN + c0],     acc0);
                    atomicAdd(&agg[prow * HIDDEN + c0 + 1], acc1);
                    acc0 = 0.0f; acc1 = 0.0f;
                    prow = s_rowbuf[wave][i];
                }
                acc0 += lo.f; acc1 += hi.f;
            }
            atomicAdd(&agg[prow * HIDDEN + c0],     acc0);
            atomicAdd(&agg[prow * HIDDEN + c0 + 1], acc1);
        }
    }
}

// ---------------------------------------------------------------------------
// Node kernel (MFMA): out = h + silu(agg@iw1+b1)@iw2+b2.
// 128 blocks: weight staging amortized over ~6 tiles/wave.
// ---------------------------------------------------------------------------
__global__ __launch_bounds__(256) void node_mfma_kernel(
    const float* __restrict__ h,
    const float* __restrict__ agg,
    const float* __restrict__ iw1,
    const float* __restrict__ ib1,
    const float* __restrict__ iw2,
    const float* __restrict__ ib2,
    float* __restrict__ out,
    int n_nodes)
{
    __shared__ __attribute__((aligned(16))) unsigned short w2T[128 * PK2];
    __shared__ __attribute__((aligned(16))) unsigned short tbuf[4 * 16 * PT];

    const int tid  = threadIdx.x;
    const int wave = tid >> 6;
    const int lane = tid & 63;
    const int l15  = lane & 15;
    const int quad = lane >> 4;

    for (int idx = tid; idx < HIDDEN * HIDDEN; idx += 256) {
        const int k = idx >> 7, n = idx & 127;
        w2T[n * PK2 + k] = f2bf(iw2[idx]);
    }

    short8 b1[4][8];
#pragma unroll
    for (int kit = 0; kit < 4; ++kit)
#pragma unroll
        for (int nt = 0; nt < 8; ++nt) {
            short8 f;
#pragma unroll
            for (int j = 0; j < 8; ++j) {
                const int k = kit * 32 + quad * 8 + j;
                f[j] = (short)f2bf(iw1[k * HIDDEN + nt * 16 + l15]);
            }
            b1[kit][nt] = f;
        }

    float ib1v[8], ib2v[8];
#pragma unroll
    for (int nt = 0; nt < 8; ++nt) {
        ib1v[nt] = ib1[nt * 16 + l15];
        ib2v[nt] = ib2[nt * 16 + l15];
    }

    __syncthreads();

    unsigned short* twave = &tbuf[wave * 16 * PT];
    const int tiles = (n_nodes + 15) >> 4;

    for (int tile = blockIdx.x * 4 + wave; tile < tiles; tile += gridDim.x * 4) {
        const int m0 = tile * 16;

        const int mA = min(m0 + l15, n_nodes - 1);
        short8 a1[4];
#pragma unroll
        for (int kit = 0; kit < 4; ++kit) {
            const float* p = &agg[mA * HIDDEN + kit * 32 + quad * 8];
            short8 f;
#pragma unroll
            for (int j = 0; j < 8; ++j) f[j] = (short)f2bf(p[j]);
            a1[kit] = f;
        }

        int mo[4]; float hres[4][8];
#pragma unroll
        for (int r = 0; r < 4; ++r) {
            mo[r] = m0 + quad * 4 + r;
            const int mc = min(mo[r], n_nodes - 1);
#pragma unroll
            for (int nt = 0; nt < 8; ++nt)
                hres[r][nt] = h[mc * HIDDEN + nt * 16 + l15];
        }

#pragma unroll
        for (int nt = 0; nt < 8; ++nt) {
            floatx4 c = {ib1v[nt], ib1v[nt], ib1v[nt], ib1v[nt]};
#pragma unroll
            for (int kit = 0; kit < 4; ++kit)
                c = __builtin_amdgcn_mfma_f32_16x16x32_bf16(a1[kit], b1[kit][nt], c, 0, 0, 0);
#pragma unroll
            for (int r = 0; r < 4; ++r)
                twave[(quad * 4 + r) * PT + nt * 16 + l15] = f2bf(silu(c[r]));
        }

        short8 a2[4];
#pragma unroll
        for (int kit = 0; kit < 4; ++kit)
            a2[kit] = *(const short8*)&twave[l15 * PT + kit * 32 + quad * 8];

#pragma unroll
        for (int nt = 0; nt < 8; ++nt) {
            floatx4 c = {ib2v[nt], ib2v[nt], ib2v[nt], ib2v[nt]};
#pragma unroll
            for (int kit = 0; kit < 4; ++kit) {
                const short8 b =
                    *(const short8*)&w2T[(nt * 16 + l15) * PK2 + kit * 32 + quad * 8];
                c = __builtin_amdgcn_mfma_f32_16x16x32_bf16(a2[kit], b, c, 0, 0, 0);
            }
            const int chan = nt * 16 + l15;
#pragma unroll
            for (int r = 0; r < 4; ++r)
                if (mo[r] < n_nodes)
                    out[mo[r] * HIDDEN + chan] = hres[r][nt] + c[r];
        }
    }
}

extern "C" void kernel_launch(void* const* d_in, const int* in_sizes, int n_in,
                              void* d_out, int out_size, void* d_ws, size_t ws_size,
                              hipStream_t stream)
{
    const float* h   = (const float*)d_in[0];
    const float* pos = (const float*)d_in[1];
    const int*   ei  = (const int*)d_in[2];
    const float* fw1 = (const float*)d_in[3];
    const float* fb1 = (const float*)d_in[4];
    const float* fw2 = (const float*)d_in[5];
    const float* fb2 = (const float*)d_in[6];
    const float* iw1 = (const float*)d_in[7];
    const float* ib1 = (const float*)d_in[8];
    const float* iw2 = (const float*)d_in[9];
    const float* ib2 = (const float*)d_in[10];
    float* out = (float*)d_out;

    const int n_nodes = in_sizes[0] / HIDDEN;
    const int n_edges = in_sizes[2] / 2;
    const int nscan   = (n_nodes + 255) >> 8;   // scanA blocks (<=256 required)

    const size_t need = (size_t)n_nodes * HIDDEN * sizeof(float);
    const bool use_ws = (d_ws != nullptr) && (ws_size >= need);

    // sort scratch layout in d_out (ints): cnt[nb] cursor[nb] btot[256]
    // boff[256] rc[2E] sdist[E]
    const size_t scratch_ints = (size_t)2 * n_nodes + 512 + (size_t)3 * n_edges;
    const bool can_sort = use_ws && nscan <= 256 &&
                          ((size_t)out_size >= scratch_ints);

    if (can_sort) {
        float* agg    = (float*)d_ws;
        int*   base   = (int*)d_out;
        int*   cnt    = base;
        int*   cursor = base + n_nodes;
        int*   btot   = base + 2 * n_nodes;
        int*   boff   = btot + 256;
        int2*  rc     = (int2*)(boff + 256);
        float* sdist  = (float*)(boff + 256 + 2 * n_edges);

        hipMemsetAsync(cnt, 0, (size_t)n_nodes * sizeof(int), stream);
        hipMemsetAsync(agg, 0, need, stream);

        hist_kernel<<<1024, 256, 0, stream>>>(ei, cnt, n_nodes, n_edges);
        scanA_kernel<<<nscan, 256, 0, stream>>>(cnt, cursor, btot, n_nodes);
        scanB_kernel<<<1, 256, 0, stream>>>(btot, boff, nscan);
        scatter_kernel<<<1024, 256, 0, stream>>>(ei, pos, cursor, boff,
                                                 rc, sdist, n_nodes, n_edges);

        edge_mfma_kernel<true><<<1536, 256, 0, stream>>>(
            h, pos, ei, rc, sdist,
            fw1, fb1, fw2, fb2, agg, n_nodes, n_edges);

        node_mfma_kernel<<<128, 256, 0, stream>>>(h, agg, iw1, ib1, iw2, ib2,
                                                  out, n_nodes);
    } else {
        float* agg = use_ws ? (float*)d_ws : out;
        hipMemsetAsync(agg, 0, need, stream);
        edge_mfma_kernel<false><<<1536, 256, 0, stream>>>(
            h, pos, ei, nullptr, nullptr,
            fw1, fb1, fw2, fb2, agg, n_nodes, n_edges);
        node_mfma_kernel<<<128, 256, 0, stream>>>(h, agg, iw1, ib1, iw2, ib2,
                                                  out, n_nodes);
    }
}